// Round 1
// baseline (239.998 us; speedup 1.0000x reference)
//
#include <hip/hip_runtime.h>

#define B_ 2
#define T_ 4096
#define E_ 768
#define H_ 12
#define S_ 64
#define WIN_ 256

typedef unsigned short u16;
typedef unsigned int u32;
typedef __attribute__((ext_vector_type(8))) short bf16x8;
typedef __attribute__((ext_vector_type(4))) short bf16x4;
typedef __attribute__((ext_vector_type(4))) float f32x4;

__device__ __forceinline__ u16 f2bf(float f) {
  u32 u = __float_as_uint(f);
  u += ((u >> 16) & 1u) + 0x7fffu;   // RNE
  return (u16)(u >> 16);
}

__device__ __forceinline__ void async_copy16(const u16* g, u16* l) {
  __builtin_amdgcn_global_load_lds(
      (const __attribute__((address_space(1))) void*)g,
      (__attribute__((address_space(3))) void*)l, 16, 0, 0);
}

// ---------------- fp32 -> bf16 conversion ----------------
__global__ void cvt_kernel(const float* __restrict__ src, u16* __restrict__ dst, int n4) {
  int i = blockIdx.x * blockDim.x + threadIdx.x;
  if (i >= n4) return;
  float4 v = ((const float4*)src)[i];
  ushort4 o;
  o.x = f2bf(v.x); o.y = f2bf(v.y); o.z = f2bf(v.z); o.w = f2bf(v.w);
  ((ushort4*)dst)[i] = o;
}

// ---------------- QKV projection GEMM: C[m,n] = scale * sum_k A[m,k]*W[n,k] ----------------
// m97-style: 128x128 tile, BK=32, global_load_lds(16B), chunk-plane LDS layout.
__global__ __launch_bounds__(256, 2)
void gemm_qkv(const u16* __restrict__ xb, const u16* __restrict__ wb,
              u16* __restrict__ qkv) {
  const int M = B_ * T_;
  __shared__ u16 As[4][128][8];   // [kchunk][row][8] : 8KB
  __shared__ u16 Bs[4][128][8];
  int tid = threadIdx.x;
  int lane = tid & 63, wave = tid >> 6;
  int wr = wave >> 1, wc = wave & 1;
  int q8 = lane >> 4, nl = lane & 15;
  int bm = blockIdx.x * 128, bn = blockIdx.y * 128;
  int z = blockIdx.z;  // 0=q,1=k,2=v
  const u16* A = xb;
  const u16* Bmat = wb + (size_t)z * E_ * E_;
  u16* C = qkv + (size_t)z * M * E_;
  // fold 1/sqrt(64) and log2(e) into q so softmax can use exp2
  float scale = (z == 0) ? (0.125f * 1.44269504088896f) : 1.0f;

  f32x4 acc[4][4] = {};
  for (int k0 = 0; k0 < E_; k0 += 32) {
    __syncthreads();
#pragma unroll
    for (int j = 0; j < 2; ++j) {
      int u = tid + j * 256;
      int ch = u >> 7, row = u & 127;
      async_copy16(A + (size_t)(bm + row) * E_ + k0 + ch * 8, &As[ch][row][0]);
      async_copy16(Bmat + (size_t)(bn + row) * E_ + k0 + ch * 8, &Bs[ch][row][0]);
    }
    __syncthreads();
    bf16x8 af[4], bfr[4];
#pragma unroll
    for (int i = 0; i < 4; ++i)
      af[i] = *(const bf16x8*)&As[q8][wr * 64 + i * 16 + nl][0];
#pragma unroll
    for (int i = 0; i < 4; ++i)
      bfr[i] = *(const bf16x8*)&Bs[q8][wc * 64 + i * 16 + nl][0];
#pragma unroll
    for (int i = 0; i < 4; ++i)
#pragma unroll
      for (int j2 = 0; j2 < 4; ++j2)
        acc[i][j2] = __builtin_amdgcn_mfma_f32_16x16x32_bf16(af[i], bfr[j2], acc[i][j2], 0, 0, 0);
  }
#pragma unroll
  for (int i = 0; i < 4; ++i)
#pragma unroll
    for (int j2 = 0; j2 < 4; ++j2)
#pragma unroll
      for (int r = 0; r < 4; ++r) {
        int row = bm + wr * 64 + i * 16 + q8 * 4 + r;
        int col = bn + wc * 64 + j2 * 16 + nl;
        C[(size_t)row * E_ + col] = f2bf(acc[i][j2][r] * scale);
      }
}

// ---------------- banded flash attention ----------------
// grid: (T/128, B*H). block 256 = 4 waves; each wave owns 32 queries (2 m-tiles).
__global__ __launch_bounds__(256, 2)
void attn_kernel(const u16* __restrict__ qkv, float* __restrict__ out) {
  const int Mtot = B_ * T_;
  const u16* qb = qkv;
  const u16* kb = qkv + (size_t)Mtot * E_;
  const u16* vb = qkv + (size_t)2 * Mtot * E_;

  __shared__ u16 Ks[8][32][8];        // [dchunk][key][8]   4KB
  __shared__ u16 Vt[64][36];          // [dim][key] stride 36 (bank-spread) 4.5KB
  __shared__ u16 Pl[4][2][4][16][8];  // [wave][mt][kchunk][row][8] 8KB

  int tid = threadIdx.x;
  int lane = tid & 63, wave = tid >> 6;
  int q8 = lane >> 4, nl = lane & 15;
  int qs = blockIdx.x * 128;
  int bh = blockIdx.y;
  int b = bh / H_, h = bh % H_;
  int qw = qs + wave * 32;
  size_t headoff = (size_t)h * S_;

  // Q fragments (A-layout): row m = nl, k = q8*8+j ; lo = d[0,32), hi = d[32,64)
  bf16x8 aq[2][2];
#pragma unroll
  for (int mt = 0; mt < 2; ++mt) {
    const u16* qrow = qb + (size_t)(b * T_ + qw + mt * 16 + nl) * E_ + headoff;
    aq[mt][0] = *(const bf16x8*)(qrow + q8 * 8);
    aq[mt][1] = *(const bf16x8*)(qrow + 32 + q8 * 8);
  }

  f32x4 O[2][4] = {};
  float mrow[2][4], lrow[2][4];
#pragma unroll
  for (int mt = 0; mt < 2; ++mt)
#pragma unroll
    for (int r = 0; r < 4; ++r) { mrow[mt][r] = -1e30f; lrow[mt][r] = 0.f; }

  for (int kt = qs - WIN_; kt < qs + 128 + WIN_; kt += 32) {
    if (kt < 0 || kt >= T_) continue;   // uniform across block
    __syncthreads();
    if (tid < 128) {
      // stage K: 256 slots of 16B, slot u: dchunk=u>>5, key=u&31
#pragma unroll
      for (int j = 0; j < 2; ++j) {
        int u = tid + j * 128;
        int ch = u >> 5, key = u & 31;
        async_copy16(kb + (size_t)(b * T_ + kt + key) * E_ + headoff + ch * 8,
                     &Ks[ch][key][0]);
      }
    } else {
      // stage V transposed: thread = (key pair, dchunk); packed u32 writes
      int t2 = tid - 128;
      int kp = t2 & 15, dc = t2 >> 4;  // dc 0..7
      const u16* v0 = vb + (size_t)(b * T_ + kt + 2 * kp) * E_ + headoff + dc * 8;
      bf16x8 va = *(const bf16x8*)v0;
      bf16x8 vb8 = *(const bf16x8*)(v0 + E_);
#pragma unroll
      for (int j = 0; j < 8; ++j) {
        u32 pk = (u32)(u16)va[j] | ((u32)(u16)vb8[j] << 16);
        *(u32*)&Vt[dc * 8 + j][2 * kp] = pk;
      }
    }
    __syncthreads();

    // wave fully out of band -> skip compute (barrier counts still match)
    if (kt + 31 < qw - WIN_ || kt > qw + 31 + WIN_) continue;

    // ---- QK^T ----
    f32x4 sc[2][2] = {};
#pragma unroll
    for (int nt = 0; nt < 2; ++nt) {
      bf16x8 bk0 = *(const bf16x8*)&Ks[q8][nt * 16 + nl][0];
      bf16x8 bk1 = *(const bf16x8*)&Ks[4 + q8][nt * 16 + nl][0];
#pragma unroll
      for (int mt = 0; mt < 2; ++mt) {
        sc[mt][nt] = __builtin_amdgcn_mfma_f32_16x16x32_bf16(aq[mt][0], bk0, sc[mt][nt], 0, 0, 0);
        sc[mt][nt] = __builtin_amdgcn_mfma_f32_16x16x32_bf16(aq[mt][1], bk1, sc[mt][nt], 0, 0, 0);
      }
    }

    // ---- band mask (only on edge tiles) ----
    if (kt < qw - 225 || kt > qw + 225) {
#pragma unroll
      for (int mt = 0; mt < 2; ++mt)
#pragma unroll
        for (int nt = 0; nt < 2; ++nt)
#pragma unroll
          for (int r = 0; r < 4; ++r) {
            int qa = qw + mt * 16 + q8 * 4 + r;
            int ka = kt + nt * 16 + nl;
            int d = ka - qa;
            sc[mt][nt][r] = (d < -WIN_ || d > WIN_) ? -1e30f : sc[mt][nt][r];
          }
    }

    // ---- online softmax (scores already in log2 domain) ----
#pragma unroll
    for (int mt = 0; mt < 2; ++mt) {
      float mn[4], al[4];
#pragma unroll
      for (int r = 0; r < 4; ++r) {
        float t = fmaxf(sc[mt][0][r], sc[mt][1][r]);
        t = fmaxf(t, __shfl_xor(t, 1));
        t = fmaxf(t, __shfl_xor(t, 2));
        t = fmaxf(t, __shfl_xor(t, 4));
        t = fmaxf(t, __shfl_xor(t, 8));
        mn[r] = fmaxf(mrow[mt][r], t);
        al[r] = exp2f(mrow[mt][r] - mn[r]);
        mrow[mt][r] = mn[r];
      }
#pragma unroll
      for (int r = 0; r < 4; ++r) {
        float p0 = exp2f(sc[mt][0][r] - mn[r]);
        float p1 = exp2f(sc[mt][1][r] - mn[r]);
        sc[mt][0][r] = p0; sc[mt][1][r] = p1;
        float s = p0 + p1;
        s += __shfl_xor(s, 1); s += __shfl_xor(s, 2);
        s += __shfl_xor(s, 4); s += __shfl_xor(s, 8);
        lrow[mt][r] = lrow[mt][r] * al[r] + s;
      }
#pragma unroll
      for (int dt = 0; dt < 4; ++dt)
#pragma unroll
        for (int r = 0; r < 4; ++r)
          O[mt][dt][r] *= al[r];
      // P (C-layout) -> LDS chunk-plane (A-layout source)
#pragma unroll
      for (int nt = 0; nt < 2; ++nt) {
        int chunk = nt * 2 + (nl >> 3);
        int cw = nl & 7;
#pragma unroll
        for (int r = 0; r < 4; ++r)
          Pl[wave][mt][chunk][q8 * 4 + r][cw] = f2bf(sc[mt][nt][r]);
      }
    }

    // ---- P @ V ----
    bf16x8 ap[2];
    ap[0] = *(const bf16x8*)&Pl[wave][0][q8][nl][0];
    ap[1] = *(const bf16x8*)&Pl[wave][1][q8][nl][0];
#pragma unroll
    for (int dt = 0; dt < 4; ++dt) {
      const u16* vp = &Vt[dt * 16 + nl][q8 * 8];
      bf16x4 lo = *(const bf16x4*)vp;
      bf16x4 hi = *(const bf16x4*)(vp + 4);
      bf16x8 bv;
      bv[0] = lo[0]; bv[1] = lo[1]; bv[2] = lo[2]; bv[3] = lo[3];
      bv[4] = hi[0]; bv[5] = hi[1]; bv[6] = hi[2]; bv[7] = hi[3];
#pragma unroll
      for (int mt = 0; mt < 2; ++mt)
        O[mt][dt] = __builtin_amdgcn_mfma_f32_16x16x32_bf16(ap[mt], bv, O[mt][dt], 0, 0, 0);
    }
  }

  // ---- normalize + store fp32 ----
#pragma unroll
  for (int mt = 0; mt < 2; ++mt)
#pragma unroll
    for (int r = 0; r < 4; ++r) {
      int qa = qw + mt * 16 + q8 * 4 + r;
      float inv = 1.0f / lrow[mt][r];
      float* op = out + (size_t)(b * T_ + qa) * E_ + headoff;
#pragma unroll
      for (int dt = 0; dt < 4; ++dt)
        op[dt * 16 + nl] = O[mt][dt][r] * inv;
    }
}

extern "C" void kernel_launch(void* const* d_in, const int* in_sizes, int n_in,
                              void* d_out, int out_size, void* d_ws, size_t ws_size,
                              hipStream_t stream) {
  const float* x  = (const float*)d_in[0];
  const float* Wq = (const float*)d_in[1];
  const float* Wk = (const float*)d_in[2];
  const float* Wv = (const float*)d_in[3];
  float* out = (float*)d_out;

  const size_t M = (size_t)B_ * T_;   // 8192
  u16* xb  = (u16*)d_ws;              // M*E bf16
  u16* wb  = xb + M * E_;             // 3*E*E bf16
  u16* qkv = wb + 3 * (size_t)E_ * E_;// 3*M*E bf16 (q scaled by 0.125*log2e)

  int n4x = (int)(M * E_ / 4);
  cvt_kernel<<<(n4x + 255) / 256, 256, 0, stream>>>(x, xb, n4x);
  int n4w = E_ * E_ / 4;
  cvt_kernel<<<(n4w + 255) / 256, 256, 0, stream>>>(Wq, wb, n4w);
  cvt_kernel<<<(n4w + 255) / 256, 256, 0, stream>>>(Wk, wb + (size_t)E_ * E_, n4w);
  cvt_kernel<<<(n4w + 255) / 256, 256, 0, stream>>>(Wv, wb + 2 * (size_t)E_ * E_, n4w);

  dim3 g1(M / 128, E_ / 128, 3);
  gemm_qkv<<<g1, 256, 0, stream>>>(xb, wb, qkv);

  dim3 g2(T_ / 128, B_ * H_);
  attn_kernel<<<g2, 256, 0, stream>>>(qkv, out);
}

// Round 2
// 215.174 us; speedup vs baseline: 1.1154x; 1.1154x over previous
//
#include <hip/hip_runtime.h>

#define B_ 2
#define T_ 4096
#define E_ 768
#define H_ 12
#define S_ 64
#define WIN_ 256

typedef unsigned short u16;
typedef unsigned int u32;
typedef __attribute__((ext_vector_type(8))) short bf16x8;
typedef __attribute__((ext_vector_type(4))) short bf16x4;
typedef __attribute__((ext_vector_type(4))) float f32x4;

__device__ __forceinline__ u16 f2bf(float f) {
  u32 u = __float_as_uint(f);
  u += ((u >> 16) & 1u) + 0x7fffu;   // RNE
  return (u16)(u >> 16);
}

__device__ __forceinline__ void async_copy16(const u16* g, u16* l) {
  __builtin_amdgcn_global_load_lds(
      (const __attribute__((address_space(1))) void*)g,
      (__attribute__((address_space(3))) void*)l, 16, 0, 0);
}

// ---------------- fp32 -> bf16, all 4 tensors in one dispatch ----------------
__global__ void cvt_all(const float* __restrict__ x, const float* __restrict__ wq,
                        const float* __restrict__ wk, const float* __restrict__ wv,
                        u16* __restrict__ xb, u16* __restrict__ wb) {
  const int n4x = B_ * T_ * E_ / 4;
  const int n4w = E_ * E_ / 4;
  int i = blockIdx.x * 256 + threadIdx.x;
  const float* src;
  u16* dst;
  int j;
  if (i < n4x) {
    src = x; dst = xb; j = i;
  } else {
    int t = i - n4x;
    int z = t / n4w;
    if (z >= 3) return;
    j = t - z * n4w;
    src = (z == 0) ? wq : ((z == 1) ? wk : wv);
    dst = wb + (size_t)z * E_ * E_;
  }
  float4 v = ((const float4*)src)[j];
  ushort4 o;
  o.x = f2bf(v.x); o.y = f2bf(v.y); o.z = f2bf(v.z); o.w = f2bf(v.w);
  ((ushort4*)dst)[j] = o;
}

// ---------------- QKV projection GEMM (m97 structure, unchanged) ----------------
__global__ __launch_bounds__(256, 2)
void gemm_qkv(const u16* __restrict__ xb, const u16* __restrict__ wb,
              u16* __restrict__ qkv) {
  const int M = B_ * T_;
  __shared__ u16 As[4][128][8];
  __shared__ u16 Bs[4][128][8];
  int tid = threadIdx.x;
  int lane = tid & 63, wave = tid >> 6;
  int wr = wave >> 1, wc = wave & 1;
  int q8 = lane >> 4, nl = lane & 15;
  int bm = blockIdx.x * 128, bn = blockIdx.y * 128;
  int z = blockIdx.z;
  const u16* A = xb;
  const u16* Bmat = wb + (size_t)z * E_ * E_;
  u16* C = qkv + (size_t)z * M * E_;
  float scale = (z == 0) ? (0.125f * 1.44269504088896f) : 1.0f;

  f32x4 acc[4][4] = {};
  for (int k0 = 0; k0 < E_; k0 += 32) {
    __syncthreads();
#pragma unroll
    for (int j = 0; j < 2; ++j) {
      int u = tid + j * 256;
      int ch = u >> 7, row = u & 127;
      async_copy16(A + (size_t)(bm + row) * E_ + k0 + ch * 8, &As[ch][row][0]);
      async_copy16(Bmat + (size_t)(bn + row) * E_ + k0 + ch * 8, &Bs[ch][row][0]);
    }
    __syncthreads();
    bf16x8 af[4], bfr[4];
#pragma unroll
    for (int i = 0; i < 4; ++i)
      af[i] = *(const bf16x8*)&As[q8][wr * 64 + i * 16 + nl][0];
#pragma unroll
    for (int i = 0; i < 4; ++i)
      bfr[i] = *(const bf16x8*)&Bs[q8][wc * 64 + i * 16 + nl][0];
#pragma unroll
    for (int i = 0; i < 4; ++i)
#pragma unroll
      for (int j2 = 0; j2 < 4; ++j2)
        acc[i][j2] = __builtin_amdgcn_mfma_f32_16x16x32_bf16(af[i], bfr[j2], acc[i][j2], 0, 0, 0);
  }
#pragma unroll
  for (int i = 0; i < 4; ++i)
#pragma unroll
    for (int j2 = 0; j2 < 4; ++j2)
#pragma unroll
      for (int r = 0; r < 4; ++r) {
        int row = bm + wr * 64 + i * 16 + q8 * 4 + r;
        int col = bn + wc * 64 + j2 * 16 + nl;
        C[(size_t)row * E_ + col] = f2bf(acc[i][j2][r] * scale);
      }
}

// ---------------- V transpose: v[b*T+t][e] -> vT[b][e][t] ----------------
__global__ void transpose_v(const u16* __restrict__ v, u16* __restrict__ vT) {
  __shared__ u16 lt[64][66];   // pad 66: scatter-writes 2-way, gather-reads 4-way
  int t = threadIdx.x;
  int t0 = blockIdx.x * 64;
  int e0 = blockIdx.y * 64;
  int b = blockIdx.z;
#pragma unroll
  for (int i = 0; i < 2; ++i) {
    int u = t + i * 256;
    int tok = u >> 3, cg = u & 7;
    bf16x8 val = *(const bf16x8*)(v + (size_t)(b * T_ + t0 + tok) * E_ + e0 + cg * 8);
#pragma unroll
    for (int j = 0; j < 8; ++j) lt[tok][cg * 8 + j] = (u16)val[j];
  }
  __syncthreads();
#pragma unroll
  for (int i = 0; i < 2; ++i) {
    int u = t + i * 256;
    int d = u >> 3, ck = u & 7;
    bf16x8 o;
#pragma unroll
    for (int j = 0; j < 8; ++j) o[j] = (short)lt[ck * 8 + j][d];
    *(bf16x8*)(vT + (size_t)(b * E_ + e0 + d) * T_ + t0 + ck * 8) = o;
  }
}

// ---------------- banded flash attention, barrier-free ----------------
// grid (T/128, B*H), 256 threads = 4 independent waves, 32 queries each.
__global__ __launch_bounds__(256, 2)
void attn_kernel(const u16* __restrict__ qkv, const u16* __restrict__ vT,
                 float* __restrict__ out) {
  const int Mtot = B_ * T_;
  const u16* qb = qkv;
  const u16* kb = qkv + (size_t)Mtot * E_;

  __shared__ u16 Pl[4][2][16][36];   // per-wave P roundtrip; pad 36 -> free writes

  int tid = threadIdx.x;
  int lane = tid & 63, wave = tid >> 6;
  int q8 = lane >> 4, nl = lane & 15;
  int qs = blockIdx.x * 128;
  int bh = blockIdx.y;
  int b = bh / H_, h = bh % H_;
  int qw = qs + wave * 32;
  size_t ho = (size_t)h * S_;

  // Q A-frags
  bf16x8 aq[2][2];
#pragma unroll
  for (int mt = 0; mt < 2; ++mt) {
    const u16* qrow = qb + (size_t)(b * T_ + qw + mt * 16 + nl) * E_ + ho;
    aq[mt][0] = *(const bf16x8*)(qrow + q8 * 8);
    aq[mt][1] = *(const bf16x8*)(qrow + 32 + q8 * 8);
  }

  f32x4 O[2][4] = {};
  f32x4 lacc[2] = {};   // deferred per-lane softmax denominator partials

  int klo = qw - WIN_; if (klo < 0) klo = 0;
  int khi = qw + 32 + WIN_; if (khi > T_) khi = T_;

  const u16* kbase = kb + (size_t)b * T_ * E_ + ho;
  const u16* vbase = vT + (size_t)b * E_ * T_ + ho * T_;

  for (int kt = klo; kt < khi; kt += 32) {
    // ---- K B-frags direct from global ----
    bf16x8 bk[2][2];
#pragma unroll
    for (int nt = 0; nt < 2; ++nt) {
      const u16* krow = kbase + (size_t)(kt + nt * 16 + nl) * E_;
      bk[nt][0] = *(const bf16x8*)(krow + q8 * 8);
      bk[nt][1] = *(const bf16x8*)(krow + 32 + q8 * 8);
    }

    // ---- QK^T ----
    f32x4 sc[2][2] = {};
#pragma unroll
    for (int nt = 0; nt < 2; ++nt)
#pragma unroll
      for (int mt = 0; mt < 2; ++mt) {
        sc[mt][nt] = __builtin_amdgcn_mfma_f32_16x16x32_bf16(aq[mt][0], bk[nt][0], sc[mt][nt], 0, 0, 0);
        sc[mt][nt] = __builtin_amdgcn_mfma_f32_16x16x32_bf16(aq[mt][1], bk[nt][1], sc[mt][nt], 0, 0, 0);
      }

    // ---- band mask on edge tiles only (wave-uniform branch) ----
    if (kt < qw - 225 || kt > qw + 225) {
#pragma unroll
      for (int mt = 0; mt < 2; ++mt)
#pragma unroll
        for (int nt = 0; nt < 2; ++nt)
#pragma unroll
          for (int r = 0; r < 4; ++r) {
            int qa = qw + mt * 16 + q8 * 4 + r;
            int ka = kt + nt * 16 + nl;
            int d = ka - qa;
            sc[mt][nt][r] = (d < -WIN_ || d > WIN_) ? -1e30f : sc[mt][nt][r];
          }
    }

    // ---- fixed-shift softmax: p = exp2(score), defer normalization ----
#pragma unroll
    for (int mt = 0; mt < 2; ++mt)
#pragma unroll
      for (int r = 0; r < 4; ++r) {
        float p0 = exp2f(sc[mt][0][r]);
        float p1 = exp2f(sc[mt][1][r]);
        sc[mt][0][r] = p0; sc[mt][1][r] = p1;
        lacc[mt][r] += p0 + p1;
      }

    // ---- P -> LDS (C-layout -> row-major A source), per-wave, no barrier ----
#pragma unroll
    for (int mt = 0; mt < 2; ++mt)
#pragma unroll
      for (int r = 0; r < 4; ++r) {
        Pl[wave][mt][q8 * 4 + r][nl] = f2bf(sc[mt][0][r]);
        Pl[wave][mt][q8 * 4 + r][16 + nl] = f2bf(sc[mt][1][r]);
      }

    bf16x8 ap[2];
#pragma unroll
    for (int mt = 0; mt < 2; ++mt) {
      bf16x4 lo = *(const bf16x4*)&Pl[wave][mt][nl][q8 * 8];
      bf16x4 hi = *(const bf16x4*)&Pl[wave][mt][nl][q8 * 8 + 4];
      bf16x8 a;
      a[0] = lo[0]; a[1] = lo[1]; a[2] = lo[2]; a[3] = lo[3];
      a[4] = hi[0]; a[5] = hi[1]; a[6] = hi[2]; a[7] = hi[3];
      ap[mt] = a;
    }

    // ---- P @ V : V B-frags direct from pre-transposed global ----
#pragma unroll
    for (int dt = 0; dt < 4; ++dt) {
      bf16x8 bv = *(const bf16x8*)(vbase + (size_t)(dt * 16 + nl) * T_ + kt + q8 * 8);
#pragma unroll
      for (int mt = 0; mt < 2; ++mt)
        O[mt][dt] = __builtin_amdgcn_mfma_f32_16x16x32_bf16(ap[mt], bv, O[mt][dt], 0, 0, 0);
    }
  }

  // ---- one deferred l-reduction + normalize + store ----
#pragma unroll
  for (int mt = 0; mt < 2; ++mt)
#pragma unroll
    for (int r = 0; r < 4; ++r) {
      float l = lacc[mt][r];
      l += __shfl_xor(l, 1); l += __shfl_xor(l, 2);
      l += __shfl_xor(l, 4); l += __shfl_xor(l, 8);
      float inv = 1.0f / l;
      int qa = qw + mt * 16 + q8 * 4 + r;
      float* op = out + (size_t)(b * T_ + qa) * E_ + ho;
#pragma unroll
      for (int dt = 0; dt < 4; ++dt)
        op[dt * 16 + nl] = O[mt][dt][r] * inv;
    }
}

extern "C" void kernel_launch(void* const* d_in, const int* in_sizes, int n_in,
                              void* d_out, int out_size, void* d_ws, size_t ws_size,
                              hipStream_t stream) {
  const float* x  = (const float*)d_in[0];
  const float* Wq = (const float*)d_in[1];
  const float* Wk = (const float*)d_in[2];
  const float* Wv = (const float*)d_in[3];
  float* out = (float*)d_out;

  const size_t M = (size_t)B_ * T_;
  u16* xb  = (u16*)d_ws;               // M*E bf16; reused as vT after gemm
  u16* wb  = xb + M * E_;              // 3*E*E
  u16* qkv = wb + 3 * (size_t)E_ * E_; // 3*M*E
  u16* vT  = xb;                       // [B][E][T], overwrites xb (dead after gemm)

  const int n4x = B_ * T_ * E_ / 4;
  const int n4w = E_ * E_ / 4;
  int cvt_blocks = (n4x + 3 * n4w + 255) / 256;
  cvt_all<<<cvt_blocks, 256, 0, stream>>>(x, Wq, Wk, Wv, xb, wb);

  dim3 g1(M / 128, E_ / 128, 3);
  gemm_qkv<<<g1, 256, 0, stream>>>(xb, wb, qkv);

  dim3 gt(T_ / 64, E_ / 64, B_);
  transpose_v<<<gt, 256, 0, stream>>>(qkv + 2 * M * E_, vT);

  dim3 g2(T_ / 128, B_ * H_);
  attn_kernel<<<g2, 256, 0, stream>>>(qkv, vT, out);
}

// Round 3
// 210.954 us; speedup vs baseline: 1.1377x; 1.0200x over previous
//
#include <hip/hip_runtime.h>

#define B_ 2
#define T_ 4096
#define E_ 768
#define H_ 12
#define S_ 64
#define WIN_ 256

typedef unsigned short u16;
typedef unsigned int u32;
typedef __attribute__((ext_vector_type(8))) short bf16x8;
typedef __attribute__((ext_vector_type(4))) short bf16x4;
typedef __attribute__((ext_vector_type(4))) float f32x4;

__device__ __forceinline__ u16 f2bf(float f) {
  u32 u = __float_as_uint(f);
  u += ((u >> 16) & 1u) + 0x7fffu;   // RNE
  return (u16)(u >> 16);
}

__device__ __forceinline__ void async_copy16(const u16* g, u16* l) {
  __builtin_amdgcn_global_load_lds(
      (const __attribute__((address_space(1))) void*)g,
      (__attribute__((address_space(3))) void*)l, 16, 0, 0);
}

// ---------------- fp32 -> bf16, all 4 tensors in one dispatch ----------------
__global__ void cvt_all(const float* __restrict__ x, const float* __restrict__ wq,
                        const float* __restrict__ wk, const float* __restrict__ wv,
                        u16* __restrict__ xb, u16* __restrict__ wb) {
  const int n4x = B_ * T_ * E_ / 4;
  const int n4w = E_ * E_ / 4;
  int i = blockIdx.x * 256 + threadIdx.x;
  const float* src;
  u16* dst;
  int j;
  if (i < n4x) {
    src = x; dst = xb; j = i;
  } else {
    int t = i - n4x;
    int z = t / n4w;
    if (z >= 3) return;
    j = t - z * n4w;
    src = (z == 0) ? wq : ((z == 1) ? wk : wv);
    dst = wb + (size_t)z * E_ * E_;
  }
  float4 v = ((const float4*)src)[j];
  ushort4 o;
  o.x = f2bf(v.x); o.y = f2bf(v.y); o.z = f2bf(v.z); o.w = f2bf(v.w);
  ((ushort4*)dst)[j] = o;
}

// ---------------- QKV projection GEMM: double-buffered, 1 barrier/iter ----------------
__global__ __launch_bounds__(256)
void gemm_qkv(const u16* __restrict__ xb, const u16* __restrict__ wb,
              u16* __restrict__ qkv) {
  const int M = B_ * T_;
  __shared__ u16 As[2][4][128][8];   // [buf][kchunk][row][8]  16KB
  __shared__ u16 Bs[2][4][128][8];   // 16KB
  int tid = threadIdx.x;
  int lane = tid & 63, wave = tid >> 6;
  int wr = wave >> 1, wc = wave & 1;
  int q8 = lane >> 4, nl = lane & 15;
  int bm = blockIdx.x * 128, bn = blockIdx.y * 128;
  int z = blockIdx.z;
  const u16* A = xb;
  const u16* Bmat = wb + (size_t)z * E_ * E_;
  u16* C = qkv + (size_t)z * M * E_;
  float scale = (z == 0) ? (0.125f * 1.44269504088896f) : 1.0f;

  // staging addresses for this thread (2 A slots + 2 B slots)
  int ch0 = tid >> 7, row0 = tid & 127;
  int u1 = tid + 256;
  int ch1 = u1 >> 7, row1 = u1 & 127;
  const u16* ga0 = A + (size_t)(bm + row0) * E_ + ch0 * 8;
  const u16* ga1 = A + (size_t)(bm + row1) * E_ + ch1 * 8;
  const u16* gb0 = Bmat + (size_t)(bn + row0) * E_ + ch0 * 8;
  const u16* gb1 = Bmat + (size_t)(bn + row1) * E_ + ch1 * 8;

  const int NK = E_ / 32;   // 24
  // prologue: stage k=0 into buf 0
  async_copy16(ga0, &As[0][ch0][row0][0]);
  async_copy16(ga1, &As[0][ch1][row1][0]);
  async_copy16(gb0, &Bs[0][ch0][row0][0]);
  async_copy16(gb1, &Bs[0][ch1][row1][0]);

  f32x4 acc[4][4] = {};
  for (int ki = 0; ki < NK; ++ki) {
    int buf = ki & 1;
    __syncthreads();   // staging of buf[ki] (issued last iter) complete; prev reads done
    if (ki + 1 < NK) {
      int nb = buf ^ 1;
      int koff = (ki + 1) * 32;
      async_copy16(ga0 + koff, &As[nb][ch0][row0][0]);
      async_copy16(ga1 + koff, &As[nb][ch1][row1][0]);
      async_copy16(gb0 + koff, &Bs[nb][ch0][row0][0]);
      async_copy16(gb1 + koff, &Bs[nb][ch1][row1][0]);
    }
    bf16x8 af[4], bfr[4];
#pragma unroll
    for (int i = 0; i < 4; ++i)
      af[i] = *(const bf16x8*)&As[buf][q8][wr * 64 + i * 16 + nl][0];
#pragma unroll
    for (int i = 0; i < 4; ++i)
      bfr[i] = *(const bf16x8*)&Bs[buf][q8][wc * 64 + i * 16 + nl][0];
#pragma unroll
    for (int i = 0; i < 4; ++i)
#pragma unroll
      for (int j2 = 0; j2 < 4; ++j2)
        acc[i][j2] = __builtin_amdgcn_mfma_f32_16x16x32_bf16(af[i], bfr[j2], acc[i][j2], 0, 0, 0);
  }
#pragma unroll
  for (int i = 0; i < 4; ++i)
#pragma unroll
    for (int j2 = 0; j2 < 4; ++j2)
#pragma unroll
      for (int r = 0; r < 4; ++r) {
        int row = bm + wr * 64 + i * 16 + q8 * 4 + r;
        int col = bn + wc * 64 + j2 * 16 + nl;
        C[(size_t)row * E_ + col] = f2bf(acc[i][j2][r] * scale);
      }
}

// ---------------- V transpose: v[b*T+t][e] -> vT[b][e][t] ----------------
__global__ void transpose_v(const u16* __restrict__ v, u16* __restrict__ vT) {
  __shared__ u16 lt[64][66];
  int t = threadIdx.x;
  int t0 = blockIdx.x * 64;
  int e0 = blockIdx.y * 64;
  int b = blockIdx.z;
#pragma unroll
  for (int i = 0; i < 2; ++i) {
    int u = t + i * 256;
    int tok = u >> 3, cg = u & 7;
    bf16x8 val = *(const bf16x8*)(v + (size_t)(b * T_ + t0 + tok) * E_ + e0 + cg * 8);
#pragma unroll
    for (int j = 0; j < 8; ++j) lt[tok][cg * 8 + j] = (u16)val[j];
  }
  __syncthreads();
#pragma unroll
  for (int i = 0; i < 2; ++i) {
    int u = t + i * 256;
    int d = u >> 3, ck = u & 7;
    bf16x8 o;
#pragma unroll
    for (int j = 0; j < 8; ++j) o[j] = (short)lt[ck * 8 + j][d];
    *(bf16x8*)(vT + (size_t)(b * E_ + e0 + d) * T_ + t0 + ck * 8) = o;
  }
}

// ---------------- banded flash attention, barrier-free + register prefetch ----------------
__global__ __launch_bounds__(256)
void attn_kernel(const u16* __restrict__ qkv, const u16* __restrict__ vT,
                 float* __restrict__ out) {
  const int Mtot = B_ * T_;
  const u16* qb = qkv;
  const u16* kb = qkv + (size_t)Mtot * E_;

  __shared__ u16 Pl[4][2][16][36];

  int tid = threadIdx.x;
  int lane = tid & 63, wave = tid >> 6;
  int q8 = lane >> 4, nl = lane & 15;
  int qs = blockIdx.x * 128;
  int bh = blockIdx.y;
  int b = bh / H_, h = bh % H_;
  int qw = qs + wave * 32;
  size_t ho = (size_t)h * S_;

  bf16x8 aq[2][2];
#pragma unroll
  for (int mt = 0; mt < 2; ++mt) {
    const u16* qrow = qb + (size_t)(b * T_ + qw + mt * 16 + nl) * E_ + ho;
    aq[mt][0] = *(const bf16x8*)(qrow + q8 * 8);
    aq[mt][1] = *(const bf16x8*)(qrow + 32 + q8 * 8);
  }

  f32x4 O[2][4] = {};
  f32x4 lacc[2] = {};

  int klo = qw - WIN_; if (klo < 0) klo = 0;
  int khi = qw + 32 + WIN_; if (khi > T_) khi = T_;

  const u16* kbase = kb + (size_t)b * T_ * E_ + ho;
  const u16* vbase = vT + (size_t)b * E_ * T_ + ho * T_;

  // prefetch first K tile
  bf16x8 bk[2][2];
#pragma unroll
  for (int nt = 0; nt < 2; ++nt) {
    const u16* krow = kbase + (size_t)(klo + nt * 16 + nl) * E_;
    bk[nt][0] = *(const bf16x8*)(krow + q8 * 8);
    bk[nt][1] = *(const bf16x8*)(krow + 32 + q8 * 8);
  }

  for (int kt = klo; kt < khi; kt += 32) {
    // ---- V loads for THIS round issued early (used after ~400cy chain) ----
    bf16x8 bv[4];
#pragma unroll
    for (int dt = 0; dt < 4; ++dt)
      bv[dt] = *(const bf16x8*)(vbase + (size_t)(dt * 16 + nl) * T_ + kt + q8 * 8);

    // ---- K prefetch for NEXT round (clamped; used next iteration) ----
    int ktn = (kt + 32 < khi) ? kt + 32 : kt;
    bf16x8 nbk[2][2];
#pragma unroll
    for (int nt = 0; nt < 2; ++nt) {
      const u16* krow = kbase + (size_t)(ktn + nt * 16 + nl) * E_;
      nbk[nt][0] = *(const bf16x8*)(krow + q8 * 8);
      nbk[nt][1] = *(const bf16x8*)(krow + 32 + q8 * 8);
    }

    // ---- QK^T ----
    f32x4 sc[2][2] = {};
#pragma unroll
    for (int nt = 0; nt < 2; ++nt)
#pragma unroll
      for (int mt = 0; mt < 2; ++mt) {
        sc[mt][nt] = __builtin_amdgcn_mfma_f32_16x16x32_bf16(aq[mt][0], bk[nt][0], sc[mt][nt], 0, 0, 0);
        sc[mt][nt] = __builtin_amdgcn_mfma_f32_16x16x32_bf16(aq[mt][1], bk[nt][1], sc[mt][nt], 0, 0, 0);
      }

    // ---- band mask on edge tiles only (wave-uniform branch) ----
    if (kt < qw - 225 || kt > qw + 225) {
#pragma unroll
      for (int mt = 0; mt < 2; ++mt)
#pragma unroll
        for (int nt = 0; nt < 2; ++nt)
#pragma unroll
          for (int r = 0; r < 4; ++r) {
            int qa = qw + mt * 16 + q8 * 4 + r;
            int ka = kt + nt * 16 + nl;
            int d = ka - qa;
            sc[mt][nt][r] = (d < -WIN_ || d > WIN_) ? -1e30f : sc[mt][nt][r];
          }
    }

    // ---- fixed-shift softmax, deferred normalization ----
#pragma unroll
    for (int mt = 0; mt < 2; ++mt)
#pragma unroll
      for (int r = 0; r < 4; ++r) {
        float p0 = exp2f(sc[mt][0][r]);
        float p1 = exp2f(sc[mt][1][r]);
        sc[mt][0][r] = p0; sc[mt][1][r] = p1;
        lacc[mt][r] += p0 + p1;
      }

    // ---- P -> LDS roundtrip (C-layout -> A-layout), per-wave ----
#pragma unroll
    for (int mt = 0; mt < 2; ++mt)
#pragma unroll
      for (int r = 0; r < 4; ++r) {
        Pl[wave][mt][q8 * 4 + r][nl] = f2bf(sc[mt][0][r]);
        Pl[wave][mt][q8 * 4 + r][16 + nl] = f2bf(sc[mt][1][r]);
      }

    bf16x8 ap[2];
#pragma unroll
    for (int mt = 0; mt < 2; ++mt) {
      bf16x4 lo = *(const bf16x4*)&Pl[wave][mt][nl][q8 * 8];
      bf16x4 hi = *(const bf16x4*)&Pl[wave][mt][nl][q8 * 8 + 4];
      bf16x8 a;
      a[0] = lo[0]; a[1] = lo[1]; a[2] = lo[2]; a[3] = lo[3];
      a[4] = hi[0]; a[5] = hi[1]; a[6] = hi[2]; a[7] = hi[3];
      ap[mt] = a;
    }

    // ---- P @ V ----
#pragma unroll
    for (int dt = 0; dt < 4; ++dt)
#pragma unroll
      for (int mt = 0; mt < 2; ++mt)
        O[mt][dt] = __builtin_amdgcn_mfma_f32_16x16x32_bf16(ap[mt], bv[dt], O[mt][dt], 0, 0, 0);

    // rotate prefetch
#pragma unroll
    for (int nt = 0; nt < 2; ++nt) {
      bk[nt][0] = nbk[nt][0];
      bk[nt][1] = nbk[nt][1];
    }
  }

  // ---- deferred l-reduction + normalize + store ----
#pragma unroll
  for (int mt = 0; mt < 2; ++mt)
#pragma unroll
    for (int r = 0; r < 4; ++r) {
      float l = lacc[mt][r];
      l += __shfl_xor(l, 1); l += __shfl_xor(l, 2);
      l += __shfl_xor(l, 4); l += __shfl_xor(l, 8);
      float inv = 1.0f / l;
      int qa = qw + mt * 16 + q8 * 4 + r;
      float* op = out + (size_t)(b * T_ + qa) * E_ + ho;
#pragma unroll
      for (int dt = 0; dt < 4; ++dt)
        op[dt * 16 + nl] = O[mt][dt][r] * inv;
    }
}

extern "C" void kernel_launch(void* const* d_in, const int* in_sizes, int n_in,
                              void* d_out, int out_size, void* d_ws, size_t ws_size,
                              hipStream_t stream) {
  const float* x  = (const float*)d_in[0];
  const float* Wq = (const float*)d_in[1];
  const float* Wk = (const float*)d_in[2];
  const float* Wv = (const float*)d_in[3];
  float* out = (float*)d_out;

  const size_t M = (size_t)B_ * T_;
  u16* xb  = (u16*)d_ws;               // M*E bf16; reused as vT after gemm
  u16* wb  = xb + M * E_;              // 3*E*E
  u16* qkv = wb + 3 * (size_t)E_ * E_; // 3*M*E
  u16* vT  = xb;                       // [B][E][T]

  const int n4x = B_ * T_ * E_ / 4;
  const int n4w = E_ * E_ / 4;
  int cvt_blocks = (n4x + 3 * n4w + 255) / 256;
  cvt_all<<<cvt_blocks, 256, 0, stream>>>(x, Wq, Wk, Wv, xb, wb);

  dim3 g1(M / 128, E_ / 128, 3);
  gemm_qkv<<<g1, 256, 0, stream>>>(xb, wb, qkv);

  dim3 gt(T_ / 64, E_ / 64, B_);
  transpose_v<<<gt, 256, 0, stream>>>(qkv + 2 * M * E_, vT);

  dim3 g2(T_ / 128, B_ * H_);
  attn_kernel<<<g2, 256, 0, stream>>>(qkv, vT, out);
}